// Round 1
// baseline (175.200 us; speedup 1.0000x reference)
//
#include <hip/hip_runtime.h>
#include <hip/hip_bf16.h>

#define N_NODES 4096
#define IN_F 256
#define OUT_F 64
#define HEADS 8
#define ALPHA 0.2f

typedef short s16x8 __attribute__((ext_vector_type(8)));
typedef float f32x4 __attribute__((ext_vector_type(4)));

// ---- workspace layout (bytes) ----
#define BFRAG_OFF 0
#define BFRAG_BYTES (HEADS * 128 * 4 * 64 * 8 * 2)        // 4 MB: B-fragment-layout bf16 H
#define F1_OFF   (BFRAG_OFF + BFRAG_BYTES)
#define F2_OFF   (F1_OFF + HEADS * N_NODES * 4)
#define WA1_OFF  (F2_OFF + HEADS * N_NODES * 4)
#define WA2_OFF  (WA1_OFF + HEADS * IN_F * 4)
#define FMAX_OFF (WA2_OFF + HEADS * IN_F * 4)
#define ADJ_OFF  (FMAX_OFF + 256)                          // 2 MB bitmask

static __device__ __forceinline__ unsigned short f2bf(float f) {
  unsigned u = __float_as_uint(f);
  u += 0x7FFFu + ((u >> 16) & 1u);           // RNE; inputs are finite non-NaN
  return (unsigned short)(u >> 16);
}

// K0: wa1[h][k] = sum_f W[h][k][f]*a1[h][f]; wa2 likewise with a2
__global__ void k_wa(const float* __restrict__ W, const float* __restrict__ a,
                     float* __restrict__ wa1, float* __restrict__ wa2) {
  int h = blockIdx.x, k = threadIdx.x;
  const float* Wr = W + ((size_t)h * IN_F + k) * OUT_F;
  const float* a1 = a + (size_t)h * 2 * OUT_F;
  const float* a2 = a1 + OUT_F;
  float s1 = 0.f, s2 = 0.f;
#pragma unroll
  for (int f = 0; f < OUT_F; f += 4) {
    float4 wv = *(const float4*)(Wr + f);
    float4 v1 = *(const float4*)(a1 + f);
    float4 v2 = *(const float4*)(a2 + f);
    s1 += wv.x*v1.x + wv.y*v1.y + wv.z*v1.z + wv.w*v1.w;
    s2 += wv.x*v2.x + wv.y*v2.y + wv.z*v2.z + wv.w*v2.w;
  }
  wa1[h*IN_F + k] = s1;
  wa2[h*IN_F + k] = s2;
}

// K1: f1[h][i] = X[i]·wa1[h], f2 likewise
__global__ void k_f(const float* __restrict__ X, const float* __restrict__ wa1,
                    const float* __restrict__ wa2, float* __restrict__ f1,
                    float* __restrict__ f2) {
  int b = blockIdx.x;
  int h = b >> 4;
  int i = ((b & 15) << 8) + threadIdx.x;
  const float* xr = X + (size_t)i * IN_F;
  const float* w1 = wa1 + h * IN_F;
  const float* w2 = wa2 + h * IN_F;
  float s1 = 0.f, s2 = 0.f;
#pragma unroll 4
  for (int k = 0; k < IN_F; k += 4) {
    float4 xv = *(const float4*)(xr + k);
    float4 v1 = *(const float4*)(w1 + k);
    float4 v2 = *(const float4*)(w2 + k);
    s1 += xv.x*v1.x + xv.y*v1.y + xv.z*v1.z + xv.w*v1.w;
    s2 += xv.x*v2.x + xv.y*v2.y + xv.z*v2.z + xv.w*v2.w;
  }
  f1[h*N_NODES + i] = s1;
  f2[h*N_NODES + i] = s2;
}

// K2: F2max[h] = max_j f2[h][j]
__global__ void k_fmax(const float* __restrict__ f2, float* __restrict__ f2max) {
  int h = blockIdx.x, t = threadIdx.x;
  float m = -1e30f;
  for (int idx = t; idx < N_NODES; idx += 256) m = fmaxf(m, f2[h*N_NODES + idx]);
#pragma unroll
  for (int off = 32; off >= 1; off >>= 1) m = fmaxf(m, __shfl_xor(m, off, 64));
  __shared__ float sm[4];
  if ((t & 63) == 0) sm[t >> 6] = m;
  __syncthreads();
  if (t == 0) f2max[h] = fmaxf(fmaxf(sm[0], sm[1]), fmaxf(sm[2], sm[3]));
}

// K3: H[h] = X @ W[h], stored as bf16 in MFMA B-fragment layout:
// bfrag[((h*128 + jt)*4 + nt)*64 + (g*16+cn)][jj] = H[h][jt*32+g*8+jj][nt*16+cn]
__global__ void k_hfrag(const float* __restrict__ X, const float* __restrict__ W,
                        unsigned short* __restrict__ bfrag) {
  int h = blockIdx.x >> 7, jt = blockIdx.x & 127;
  int t = threadIdx.x;
  int c = t & 63, g = t >> 6;
  const float* Wh = W + (size_t)h * IN_F * OUT_F;
  int ibase = jt * 32 + g * 8;
  float acc[8] = {0.f,0.f,0.f,0.f,0.f,0.f,0.f,0.f};
  for (int k4 = 0; k4 < 64; ++k4) {
    float w0 = Wh[(k4*4+0)*64 + c];
    float w1 = Wh[(k4*4+1)*64 + c];
    float w2 = Wh[(k4*4+2)*64 + c];
    float w3 = Wh[(k4*4+3)*64 + c];
#pragma unroll
    for (int jj = 0; jj < 8; ++jj) {
      float4 xv = *(const float4*)(X + (size_t)(ibase+jj)*IN_F + k4*4);
      acc[jj] += xv.x*w0 + xv.y*w1 + xv.z*w2 + xv.w*w3;
    }
  }
  int nt = c >> 4, cn = c & 15;
  size_t eidx = ((((size_t)h*128 + jt)*4 + nt)*64 + (g*16+cn)) * 8;
  s16x8 hv;
#pragma unroll
  for (int jj = 0; jj < 8; ++jj) hv[jj] = (short)f2bf(acc[jj]);
  *(s16x8*)(bfrag + eidx) = hv;
}

// A2: adjacency -> bitmask, 1 bit per edge (ballot across the wave)
__global__ void k_adjbits(const int* __restrict__ adj,
                          unsigned long long* __restrict__ bits) {
  int lane = threadIdx.x & 63;
  int waveid = (int)((blockIdx.x * blockDim.x + threadIdx.x) >> 6);
  for (int it = 0; it < 32; ++it) {
    int widx = waveid + it * 8192;                 // 262144 u64 words total
    int v = adj[(size_t)widx * 64 + lane];
    unsigned long long m = __ballot(v != 0);
    if (lane == 0) bits[widx] = m;
  }
}

// K4: fused attention. 256 blocks x 512 threads; wave w <-> head w; 16-row i-tile.
__global__ __launch_bounds__(512) void k_attn(
    const float* __restrict__ f1, const float* __restrict__ f2,
    const float* __restrict__ f2max, const unsigned int* __restrict__ adjbits,
    const unsigned short* __restrict__ bfrag, float* __restrict__ out) {
  __shared__ unsigned int Lbits[16][129];
  __shared__ float Hout[HEADS][16 * 64];
  int i0 = blockIdx.x * 16;
  int t = threadIdx.x;
  int h = t >> 6, l = t & 63;
  int r = l & 15, g = l >> 4;
  for (int q = t; q < 16 * 128; q += 512)
    Lbits[q >> 7][q & 127] = adjbits[(size_t)(i0 + (q >> 7)) * 128 + (q & 127)];
  __syncthreads();
  float f1r = f1[h * N_NODES + i0 + r];
  float F2m = f2max[h];
  float sM = f1r + F2m;
  float M = fmaxf(sM, ALPHA * sM);       // upper bound of row max (monotone lrelu)
  const float* f2h = f2 + h * N_NODES;
  const s16x8* bfh = (const s16x8*)bfrag + (size_t)h * (128 * 4 * 64) + l;
  f32x4 acc0 = {0.f,0.f,0.f,0.f}, acc1 = acc0, acc2 = acc0, acc3 = acc0;
  float den = 0.f;
  for (int jt = 0; jt < 128; ++jt) {
    unsigned int mb = (Lbits[r][jt] >> (g * 8)) & 0xFFu;
    const float* fp = f2h + jt * 32 + g * 8;
    float4 fa = *(const float4*)fp;
    float4 fb = *(const float4*)(fp + 4);
    float fv[8] = {fa.x, fa.y, fa.z, fa.w, fb.x, fb.y, fb.z, fb.w};
    s16x8 av;
#pragma unroll
    for (int jj = 0; jj < 8; ++jj) {
      float s = f1r + fv[jj];
      float e = fmaxf(s, ALPHA * s);
      float p = ((mb >> jj) & 1u) ? __expf(e - M) : 0.f;
      den += p;
      av[jj] = (short)f2bf(p);
    }
    const s16x8* bp = bfh + jt * 256;
    s16x8 b0 = bp[0], b1 = bp[64], b2 = bp[128], b3 = bp[192];
    acc0 = __builtin_amdgcn_mfma_f32_16x16x32_bf16(av, b0, acc0, 0, 0, 0);
    acc1 = __builtin_amdgcn_mfma_f32_16x16x32_bf16(av, b1, acc1, 0, 0, 0);
    acc2 = __builtin_amdgcn_mfma_f32_16x16x32_bf16(av, b2, acc2, 0, 0, 0);
    acc3 = __builtin_amdgcn_mfma_f32_16x16x32_bf16(av, b3, acc3, 0, 0, 0);
  }
  den += __shfl_xor(den, 16);
  den += __shfl_xor(den, 32);            // every lane: full den for row r=l&15
#pragma unroll
  for (int ri = 0; ri < 4; ++ri) {
    int row = g * 4 + ri;                // D layout: row=(l>>4)*4+ri, col=nt*16+(l&15)
    float sc = 0.125f / __shfl(den, row);
    Hout[h][row * 64 +      r] = acc0[ri] * sc;
    Hout[h][row * 64 + 16 + r] = acc1[ri] * sc;
    Hout[h][row * 64 + 32 + r] = acc2[ri] * sc;
    Hout[h][row * 64 + 48 + r] = acc3[ri] * sc;
  }
  __syncthreads();
  for (int q = t; q < 1024; q += 512) {
    float s = 0.f;
#pragma unroll
    for (int hh = 0; hh < HEADS; ++hh) s += Hout[hh][q];
    out[(size_t)i0 * 64 + q] = s;
  }
}

extern "C" void kernel_launch(void* const* d_in, const int* in_sizes, int n_in,
                              void* d_out, int out_size, void* d_ws, size_t ws_size,
                              hipStream_t stream) {
  const float* X = (const float*)d_in[0];
  const int* adj = (const int*)d_in[1];
  const float* W = (const float*)d_in[2];
  const float* a = (const float*)d_in[3];
  float* out = (float*)d_out;
  char* ws = (char*)d_ws;

  unsigned short* bfrag = (unsigned short*)(ws + BFRAG_OFF);
  float* f1  = (float*)(ws + F1_OFF);
  float* f2  = (float*)(ws + F2_OFF);
  float* wa1 = (float*)(ws + WA1_OFF);
  float* wa2 = (float*)(ws + WA2_OFF);
  float* fmx = (float*)(ws + FMAX_OFF);
  unsigned long long* bits64 = (unsigned long long*)(ws + ADJ_OFF);
  const unsigned int* bits32 = (const unsigned int*)(ws + ADJ_OFF);

  k_wa<<<dim3(HEADS), dim3(IN_F), 0, stream>>>(W, a, wa1, wa2);
  k_hfrag<<<dim3(HEADS * 128), dim3(256), 0, stream>>>(X, W, bfrag);
  k_f<<<dim3(128), dim3(256), 0, stream>>>(X, wa1, wa2, f1, f2);
  k_fmax<<<dim3(HEADS), dim3(256), 0, stream>>>(f2, fmx);
  k_adjbits<<<dim3(2048), dim3(256), 0, stream>>>(adj, bits64);
  k_attn<<<dim3(256), dim3(512), 0, stream>>>(f1, f2, fmx, bits32, bfrag, out);
}

// Round 2
// 109.412 us; speedup vs baseline: 1.6013x; 1.6013x over previous
//
#include <hip/hip_runtime.h>
#include <hip/hip_bf16.h>

#define N_NODES 4096
#define IN_F 256
#define OUT_F 64
#define HEADS 8
#define ALPHA 0.2f

typedef short s16x8 __attribute__((ext_vector_type(8)));
typedef float f32x4 __attribute__((ext_vector_type(4)));

// ---- workspace layout (bytes) ----
#define XB_OFF    0
#define WFRAG_OFF (XB_OFF + 4096*256*2)            // 2 MB  bf16 X
#define BFRAG_OFF (WFRAG_OFF + 8*8*4*64*8*2)       // 256 KB bf16 W B-frags
#define F1_OFF    (BFRAG_OFF + 8*128*4*64*8*2)     // 4 MB  bf16 H B-frags
#define F2_OFF    (F1_OFF + 8*4096*4)
#define WA1_OFF   (F2_OFF + 8*4096*4)
#define WA2_OFF   (WA1_OFF + 8*256*4)
#define FMAX_OFF  (WA2_OFF + 8*256*4)
#define ADJ_OFF   (FMAX_OFF + 256)                 // 2 MB adjacency bitmask
#define HPART_OFF (ADJ_OFF + 2097152)              // 8 MB per-head outputs

static __device__ __forceinline__ unsigned short f2bf(float f) {
  unsigned u = __float_as_uint(f);
  u += 0x7FFFu + ((u >> 16) & 1u);           // RNE; inputs are finite non-NaN
  return (unsigned short)(u >> 16);
}

// K_prep: blocks 0..63 convert X->bf16; 64..71 compute wa1/wa2; 72..79 W B-frags
__global__ __launch_bounds__(256) void k_prep(
    const float* __restrict__ X, const float* __restrict__ W,
    const float* __restrict__ a, unsigned short* __restrict__ Xb,
    float* __restrict__ wa1, float* __restrict__ wa2,
    unsigned short* __restrict__ wfrag) {
  int b = blockIdx.x, t = threadIdx.x;
  if (b < 64) {
    int tid = b * 256 + t;
#pragma unroll
    for (int it = 0; it < 8; ++it) {
      int idx = (it * 16384 + tid) * 8;
      float4 xa = *(const float4*)(X + idx);
      float4 xc = *(const float4*)(X + idx + 4);
      s16x8 o;
      o[0] = (short)f2bf(xa.x); o[1] = (short)f2bf(xa.y);
      o[2] = (short)f2bf(xa.z); o[3] = (short)f2bf(xa.w);
      o[4] = (short)f2bf(xc.x); o[5] = (short)f2bf(xc.y);
      o[6] = (short)f2bf(xc.z); o[7] = (short)f2bf(xc.w);
      *(s16x8*)(Xb + idx) = o;
    }
  } else if (b < 72) {
    int h = b - 64, k = t;
    const float* Wr = W + ((size_t)h * IN_F + k) * OUT_F;
    const float* a1 = a + (size_t)h * 2 * OUT_F;
    const float* a2 = a1 + OUT_F;
    float s1 = 0.f, s2 = 0.f;
#pragma unroll
    for (int f = 0; f < OUT_F; f += 4) {
      float4 wv = *(const float4*)(Wr + f);
      float4 v1 = *(const float4*)(a1 + f);
      float4 v2 = *(const float4*)(a2 + f);
      s1 += wv.x*v1.x + wv.y*v1.y + wv.z*v1.z + wv.w*v1.w;
      s2 += wv.x*v2.x + wv.y*v2.y + wv.z*v2.z + wv.w*v2.w;
    }
    wa1[h*IN_F + k] = s1;
    wa2[h*IN_F + k] = s2;
  } else {
    int h = b - 72;
    for (int pos = t; pos < 2048; pos += 256) {
      int kt = pos >> 8, ct = (pos >> 6) & 3, l = pos & 63;
      int lr = l & 15, lg = l >> 4;
      s16x8 o;
#pragma unroll
      for (int e = 0; e < 8; ++e)
        o[e] = (short)f2bf(W[(size_t)(h*256 + kt*32 + lg*8 + e) * 64 + ct*16 + lr]);
      *(s16x8*)(wfrag + (size_t)(((h*8 + kt)*4 + ct)*64 + l) * 8) = o;
    }
  }
}

// adjacency -> bitmask, 1 bit per edge
__global__ __launch_bounds__(256) void k_adjbits(const int* __restrict__ adj,
                                                 unsigned long long* __restrict__ bits) {
  int lane = threadIdx.x & 63;
  int waveid = (int)((blockIdx.x * blockDim.x + threadIdx.x) >> 6);
  for (int it = 0; it < 32; ++it) {
    int widx = waveid + it * 8192;                 // 262144 u64 words total
    int v = adj[(size_t)widx * 64 + lane];
    unsigned long long m = __ballot(v != 0);
    if (lane == 0) bits[widx] = m;
  }
}

// H[h] = X @ W[h] via MFMA, output in bf16 B-fragment layout for k_attn
__global__ __launch_bounds__(256) void k_hgemm(const unsigned short* __restrict__ Xb,
                                               const unsigned short* __restrict__ wfrag,
                                               unsigned short* __restrict__ bfrag) {
  int b = blockIdx.x;
  int h = b & 7, rb = b >> 3;                      // rb 0..31, 128 rows each
  int t = threadIdx.x, w = t >> 6, l = t & 63;
  int i0 = rb * 128 + w * 32;
  int r = l & 15, g = l >> 4;
  const s16x8* xv = (const s16x8*)Xb;
  const s16x8* wv = (const s16x8*)wfrag;
  f32x4 z = {0.f, 0.f, 0.f, 0.f};
  f32x4 acc[2][4] = {{z,z,z,z},{z,z,z,z}};
#pragma unroll
  for (int kt = 0; kt < 8; ++kt) {
    s16x8 a0 = xv[(i0 + r) * 32 + kt*4 + g];
    s16x8 a1 = xv[(i0 + 16 + r) * 32 + kt*4 + g];
#pragma unroll
    for (int ct = 0; ct < 4; ++ct) {
      s16x8 bv = wv[((h*8 + kt)*4 + ct)*64 + l];
      acc[0][ct] = __builtin_amdgcn_mfma_f32_16x16x32_bf16(a0, bv, acc[0][ct], 0, 0, 0);
      acc[1][ct] = __builtin_amdgcn_mfma_f32_16x16x32_bf16(a1, bv, acc[1][ct], 0, 0, 0);
    }
  }
#pragma unroll
  for (int rt2 = 0; rt2 < 2; ++rt2)
#pragma unroll
    for (int ct = 0; ct < 4; ++ct)
#pragma unroll
      for (int ri = 0; ri < 4; ++ri) {
        int j = i0 + rt2*16 + g*4 + ri;            // D row=(l>>4)*4+ri, col=ct*16+r
        bfrag[(size_t)((((h*128 + (j>>5))*4 + ct)*64) + ((j>>3)&3)*16 + r) * 8 + (j&7)]
            = f2bf(acc[rt2][ct][ri]);
      }
}

// f1/f2 for all heads: 64 blocks x 64 rows; wave = k-quarter (uniform -> s_load wa)
__global__ __launch_bounds__(256) void k_f(const float* __restrict__ X,
                                           const float* __restrict__ wa1,
                                           const float* __restrict__ wa2,
                                           float* __restrict__ f1, float* __restrict__ f2) {
  int b = blockIdx.x, t = threadIdx.x, l = t & 63;
  int wq = __builtin_amdgcn_readfirstlane(t >> 6);
  int i = b * 64 + l;
  const float* xr = X + (size_t)i * 256 + wq * 64;
  float s1[8] = {0,0,0,0,0,0,0,0}, s2[8] = {0,0,0,0,0,0,0,0};
#pragma unroll 4
  for (int k = 0; k < 64; k += 4) {
    float4 xv = *(const float4*)(xr + k);
#pragma unroll
    for (int h = 0; h < 8; ++h) {
      float4 v1 = *(const float4*)(wa1 + h*256 + wq*64 + k);
      float4 v2 = *(const float4*)(wa2 + h*256 + wq*64 + k);
      s1[h] += xv.x*v1.x + xv.y*v1.y + xv.z*v1.z + xv.w*v1.w;
      s2[h] += xv.x*v2.x + xv.y*v2.y + xv.z*v2.z + xv.w*v2.w;
    }
  }
  __shared__ float red[3][64][16];
  if (wq > 0) {
#pragma unroll
    for (int h = 0; h < 8; ++h) {
      red[wq-1][l][h] = s1[h];
      red[wq-1][l][h+8] = s2[h];
    }
  }
  __syncthreads();
  if (wq == 0) {
#pragma unroll
    for (int h = 0; h < 8; ++h) {
#pragma unroll
      for (int q = 0; q < 3; ++q) { s1[h] += red[q][l][h]; s2[h] += red[q][l][h+8]; }
      f1[h*4096 + i] = s1[h];
      f2[h*4096 + i] = s2[h];
    }
  }
}

__global__ __launch_bounds__(256) void k_fmax(const float* __restrict__ f2,
                                              float* __restrict__ f2max) {
  int h = blockIdx.x, t = threadIdx.x;
  float m = -1e30f;
  for (int idx = t; idx < N_NODES; idx += 256) m = fmaxf(m, f2[h*N_NODES + idx]);
#pragma unroll
  for (int off = 32; off >= 1; off >>= 1) m = fmaxf(m, __shfl_xor(m, off, 64));
  __shared__ float sm[4];
  if ((t & 63) == 0) sm[t >> 6] = m;
  __syncthreads();
  if (t == 0) f2max[h] = fmaxf(fmaxf(sm[0], sm[1]), fmaxf(sm[2], sm[3]));
}

// fused attention: block = (head, 64-row tile); 8 waves = 4 row-tiles x 2 j-halves
__global__ __launch_bounds__(512) void k_attn(
    const float* __restrict__ f1, const float* __restrict__ f2,
    const float* __restrict__ f2max, const unsigned int* __restrict__ adjbits,
    const unsigned short* __restrict__ bfrag, float* __restrict__ hpart) {
  __shared__ unsigned int Lb[64][132];             // pad: stride 132 kills 16-way conflict
  __shared__ f32x4 red[4][64][4];
  __shared__ float redden[4][16];
  int b = blockIdx.x;
  int h = b & 7, rb = b >> 3;                      // head <-> XCD for L2 locality
  int i0 = rb * 64;
  int t = threadIdx.x, w = t >> 6, l = t & 63;
  int rt = w & 3, jh = w >> 2;
  int r = l & 15, g = l >> 4;
  for (int q = t; q < 64 * 128; q += 512)
    Lb[q >> 7][q & 127] = adjbits[(size_t)(i0 + (q >> 7)) * 128 + (q & 127)];
  __syncthreads();
  int irow = i0 + rt * 16 + r;
  float f1r = f1[h * N_NODES + irow];
  float F2m = f2max[h];
  float sM = f1r + F2m;
  float M = fmaxf(sM, ALPHA * sM);                 // row-max upper bound (monotone lrelu)
  const float* f2h = f2 + h * N_NODES;
  const s16x8* bfh = (const s16x8*)bfrag + (size_t)h * (128 * 4 * 64) + l;
  f32x4 z = {0.f,0.f,0.f,0.f};
  f32x4 acc0 = z, acc1 = z, acc2 = z, acc3 = z;
  float den = 0.f;
  for (int q = 0; q < 64; ++q) {
    int jt = jh * 64 + q;
    unsigned int mb = (Lb[rt*16 + r][jt] >> (g * 8)) & 0xFFu;
    const float* fp = f2h + jt * 32 + g * 8;
    float4 fa = *(const float4*)fp;
    float4 fb = *(const float4*)(fp + 4);
    float fv[8] = {fa.x, fa.y, fa.z, fa.w, fb.x, fb.y, fb.z, fb.w};
    s16x8 av;
#pragma unroll
    for (int jj = 0; jj < 8; ++jj) {
      float s = f1r + fv[jj];
      float e = fmaxf(s, ALPHA * s);
      float p = ((mb >> jj) & 1u) ? __expf(e - M) : 0.f;
      unsigned u = __float_as_uint(p);
      den += __uint_as_float(u & 0xFFFF0000u);     // den matches truncated p exactly
      av[jj] = (short)(u >> 16);
    }
    const s16x8* bp = bfh + jt * 256;
    s16x8 b0 = bp[0], b1 = bp[64], b2 = bp[128], b3 = bp[192];
    acc0 = __builtin_amdgcn_mfma_f32_16x16x32_bf16(av, b0, acc0, 0, 0, 0);
    acc1 = __builtin_amdgcn_mfma_f32_16x16x32_bf16(av, b1, acc1, 0, 0, 0);
    acc2 = __builtin_amdgcn_mfma_f32_16x16x32_bf16(av, b2, acc2, 0, 0, 0);
    acc3 = __builtin_amdgcn_mfma_f32_16x16x32_bf16(av, b3, acc3, 0, 0, 0);
  }
  den += __shfl_xor(den, 16);
  den += __shfl_xor(den, 32);                      // per-row den (this j-half)
  if (jh == 1) {
    red[rt][l][0] = acc0; red[rt][l][1] = acc1;
    red[rt][l][2] = acc2; red[rt][l][3] = acc3;
    if (l < 16) redden[rt][l] = den;
  }
  __syncthreads();
  if (jh == 0) {
    acc0 += red[rt][l][0]; acc1 += red[rt][l][1];
    acc2 += red[rt][l][2]; acc3 += red[rt][l][3];
    den += redden[rt][r];
#pragma unroll
    for (int ri = 0; ri < 4; ++ri) {
      int row = g * 4 + ri;                        // D: row=(l>>4)*4+ri, col=ct*16+r
      float sc = 0.125f / __shfl(den, row);
      float* hp = hpart + ((size_t)h * N_NODES + i0 + rt*16 + row) * 64;
      hp[r]      = acc0[ri] * sc;
      hp[16 + r] = acc1[ri] * sc;
      hp[32 + r] = acc2[ri] * sc;
      hp[48 + r] = acc3[ri] * sc;
    }
  }
}

// out = sum_h hpart[h]  (0.125 already folded into hpart)
__global__ __launch_bounds__(256) void k_hmean(const float* __restrict__ hpart,
                                               float* __restrict__ out) {
  int idx = blockIdx.x * 256 + threadIdx.x;        // 65536 float4s
  const float4* hp = (const float4*)hpart;
  float4 s = hp[idx];
#pragma unroll
  for (int h = 1; h < 8; ++h) {
    float4 v = hp[h * 65536 + idx];
    s.x += v.x; s.y += v.y; s.z += v.z; s.w += v.w;
  }
  ((float4*)out)[idx] = s;
}

extern "C" void kernel_launch(void* const* d_in, const int* in_sizes, int n_in,
                              void* d_out, int out_size, void* d_ws, size_t ws_size,
                              hipStream_t stream) {
  const float* X = (const float*)d_in[0];
  const int* adj = (const int*)d_in[1];
  const float* W = (const float*)d_in[2];
  const float* a = (const float*)d_in[3];
  float* out = (float*)d_out;
  char* ws = (char*)d_ws;

  unsigned short* Xb    = (unsigned short*)(ws + XB_OFF);
  unsigned short* wfrag = (unsigned short*)(ws + WFRAG_OFF);
  unsigned short* bfrag = (unsigned short*)(ws + BFRAG_OFF);
  float* f1  = (float*)(ws + F1_OFF);
  float* f2  = (float*)(ws + F2_OFF);
  float* wa1 = (float*)(ws + WA1_OFF);
  float* wa2 = (float*)(ws + WA2_OFF);
  float* fmx = (float*)(ws + FMAX_OFF);
  unsigned long long* bits64 = (unsigned long long*)(ws + ADJ_OFF);
  const unsigned int* bits32 = (const unsigned int*)(ws + ADJ_OFF);
  float* hpart = (float*)(ws + HPART_OFF);

  k_prep<<<dim3(80), dim3(256), 0, stream>>>(X, W, a, Xb, wa1, wa2, wfrag);
  k_adjbits<<<dim3(2048), dim3(256), 0, stream>>>(adj, bits64);
  k_hgemm<<<dim3(256), dim3(256), 0, stream>>>(Xb, wfrag, bfrag);
  k_f<<<dim3(64), dim3(256), 0, stream>>>(X, wa1, wa2, f1, f2);
  k_fmax<<<dim3(8), dim3(256), 0, stream>>>(f2, fmx);
  k_attn<<<dim3(512), dim3(512), 0, stream>>>(f1, f2, fmx, bits32, bfrag, hpart);
  k_hmean<<<dim3(256), dim3(256), 0, stream>>>(hpart, out);
}

// Round 4
// 95.751 us; speedup vs baseline: 1.8297x; 1.1427x over previous
//
#include <hip/hip_runtime.h>
#include <hip/hip_bf16.h>

#define N_NODES 4096
#define IN_F 256
#define OUT_F 64
#define HEADS 8
#define ALPHA 0.2f

typedef _Float16 f16x8 __attribute__((ext_vector_type(8)));
typedef float f32x4 __attribute__((ext_vector_type(4)));
union U4 { uint4 u; f16x8 h; unsigned w[4]; };

// ---- workspace layout (bytes) ----
#define XF_OFF    0                                 // 2 MB  f16 X
#define WFRAG_OFF (XF_OFF + 4096*256*2)             // 256 KB f16 W B-frags
#define BFRAG_OFF (WFRAG_OFF + 8*8*4*64*8*2)        // 4 MB  f16 H B-frags
#define F1_OFF    (BFRAG_OFF + 8*128*4*64*8*2)
#define F2_OFF    (F1_OFF + 8*4096*4)
#define WA1_OFF   (F2_OFF + 8*4096*4)
#define WA2_OFF   (WA1_OFF + 8*256*4)
#define FMAX_OFF  (WA2_OFF + 8*256*4)
#define GP_OFF    (FMAX_OFF + 256)                  // 64 KB f16 exp(f2)
#define GN_OFF    (GP_OFF + 8*4096*2)               // 64 KB f16 exp(a*f2)
#define ADJ_OFF   (GN_OFF + 8*4096*2)               // 2 MB adjacency bitmask
#define HPART_OFF (ADJ_OFF + 2097152)               // 8 MB per-head outputs

static __device__ __forceinline__ unsigned pkmul(unsigned a, unsigned b) {
  unsigned r; asm("v_pk_mul_f16 %0, %1, %2" : "=v"(r) : "v"(a), "v"(b)); return r;
}
static __device__ __forceinline__ unsigned pkmax(unsigned a, unsigned b) {
  unsigned r; asm("v_pk_max_f16 %0, %1, %2" : "=v"(r) : "v"(a), "v"(b)); return r;
}
static __device__ __forceinline__ unsigned short f2h_bits(float f) {
  return __builtin_bit_cast(unsigned short, (_Float16)f);
}

// k_misc: [0,2048) adj->bitmask; [2048,2112) X->f16; [2112,2120) wa; [2120,2128) W B-frags
__global__ __launch_bounds__(256) void k_misc(
    const float* __restrict__ X, const int* __restrict__ adj,
    const float* __restrict__ W, const float* __restrict__ a,
    _Float16* __restrict__ Xf, unsigned long long* __restrict__ bits,
    float* __restrict__ wa1, float* __restrict__ wa2, _Float16* __restrict__ wfrag) {
  int b = blockIdx.x, t = threadIdx.x;
  if (b < 2048) {
    int lane = t & 63;
    int waveid = b * 4 + (t >> 6);
    for (int it = 0; it < 32; ++it) {
      int widx = waveid + it * 8192;
      int v = adj[(size_t)widx * 64 + lane];
      unsigned long long m = __ballot(v != 0);
      if (lane == 0) bits[widx] = m;
    }
  } else if (b < 2112) {
    int tid = (b - 2048) * 256 + t;
#pragma unroll
    for (int it = 0; it < 8; ++it) {
      int idx = (it * 16384 + tid) * 8;
      float4 xa = *(const float4*)(X + idx);
      float4 xc = *(const float4*)(X + idx + 4);
      U4 o;
      o.h[0] = (_Float16)xa.x; o.h[1] = (_Float16)xa.y;
      o.h[2] = (_Float16)xa.z; o.h[3] = (_Float16)xa.w;
      o.h[4] = (_Float16)xc.x; o.h[5] = (_Float16)xc.y;
      o.h[6] = (_Float16)xc.z; o.h[7] = (_Float16)xc.w;
      *(U4*)(Xf + idx) = o;
    }
  } else if (b < 2120) {
    int h = b - 2112, k = t;
    const float* Wr = W + ((size_t)h * IN_F + k) * OUT_F;
    const float* a1 = a + (size_t)h * 2 * OUT_F;
    const float* a2 = a1 + OUT_F;
    float s1 = 0.f, s2 = 0.f;
#pragma unroll
    for (int f = 0; f < OUT_F; f += 4) {
      float4 wv = *(const float4*)(Wr + f);
      float4 v1 = *(const float4*)(a1 + f);
      float4 v2 = *(const float4*)(a2 + f);
      s1 += wv.x*v1.x + wv.y*v1.y + wv.z*v1.z + wv.w*v1.w;
      s2 += wv.x*v2.x + wv.y*v2.y + wv.z*v2.z + wv.w*v2.w;
    }
    wa1[h*IN_F + k] = s1;
    wa2[h*IN_F + k] = s2;
  } else {
    int h = b - 2120;
    for (int pos = t; pos < 2048; pos += 256) {
      int kt = pos >> 8, ct = (pos >> 6) & 3, l = pos & 63;
      int lr = l & 15, lg = l >> 4;
#pragma unroll
      for (int e = 0; e < 8; ++e)
        wfrag[(size_t)(((h*8 + kt)*4 + ct)*64 + l) * 8 + e]
          = (_Float16)W[(size_t)(h*256 + kt*32 + lg*8 + e) * 64 + ct*16 + lr];
    }
  }
}

// k_hf: [0,256) H=X@W (f16 MFMA) -> B-frag layout; [256,320) f1/f2
__global__ __launch_bounds__(256) void k_hf(
    const _Float16* __restrict__ Xf, const _Float16* __restrict__ wfrag,
    const float* __restrict__ X, const float* __restrict__ wa1,
    const float* __restrict__ wa2, _Float16* __restrict__ bfrag,
    float* __restrict__ f1, float* __restrict__ f2) {
  __shared__ float red[3][64][16];
  int b = blockIdx.x, t = threadIdx.x;
  if (b < 256) {
    int h = b & 7, rb = b >> 3;
    int w = t >> 6, l = t & 63;
    int i0 = rb * 128 + w * 32;
    int r = l & 15, g = l >> 4;
    const U4* xv = (const U4*)Xf;
    const U4* wv = (const U4*)wfrag;
    f32x4 z = {0.f, 0.f, 0.f, 0.f};
    f32x4 acc[2][4] = {{z,z,z,z},{z,z,z,z}};
#pragma unroll
    for (int kt = 0; kt < 8; ++kt) {
      U4 a0 = xv[(i0 + r) * 32 + kt*4 + g];
      U4 a1 = xv[(i0 + 16 + r) * 32 + kt*4 + g];
#pragma unroll
      for (int ct = 0; ct < 4; ++ct) {
        U4 bv = wv[((h*8 + kt)*4 + ct)*64 + l];
        acc[0][ct] = __builtin_amdgcn_mfma_f32_16x16x32_f16(a0.h, bv.h, acc[0][ct], 0, 0, 0);
        acc[1][ct] = __builtin_amdgcn_mfma_f32_16x16x32_f16(a1.h, bv.h, acc[1][ct], 0, 0, 0);
      }
    }
#pragma unroll
    for (int rt2 = 0; rt2 < 2; ++rt2)
#pragma unroll
      for (int ct = 0; ct < 4; ++ct)
#pragma unroll
        for (int ri = 0; ri < 4; ++ri) {
          int j = i0 + rt2*16 + g*4 + ri;
          bfrag[(size_t)((((h*128 + (j>>5))*4 + ct)*64) + ((j>>3)&3)*16 + r) * 8 + (j&7)]
              = (_Float16)acc[rt2][ct][ri];
        }
  } else {
    int bb = b - 256, l = t & 63;
    int wq = __builtin_amdgcn_readfirstlane(t >> 6);
    int i = bb * 64 + l;
    const float* xr = X + (size_t)i * 256 + wq * 64;
    float s1[8] = {0,0,0,0,0,0,0,0}, s2[8] = {0,0,0,0,0,0,0,0};
#pragma unroll 4
    for (int k = 0; k < 64; k += 4) {
      float4 xv = *(const float4*)(xr + k);
#pragma unroll
      for (int h = 0; h < 8; ++h) {
        float4 v1 = *(const float4*)(wa1 + h*256 + wq*64 + k);
        float4 v2 = *(const float4*)(wa2 + h*256 + wq*64 + k);
        s1[h] += xv.x*v1.x + xv.y*v1.y + xv.z*v1.z + xv.w*v1.w;
        s2[h] += xv.x*v2.x + xv.y*v2.y + xv.z*v2.z + xv.w*v2.w;
      }
    }
    if (wq > 0) {
#pragma unroll
      for (int h = 0; h < 8; ++h) {
        red[wq-1][l][h] = s1[h];
        red[wq-1][l][h+8] = s2[h];
      }
    }
    __syncthreads();
    if (wq == 0) {
#pragma unroll
      for (int h = 0; h < 8; ++h) {
#pragma unroll
        for (int q = 0; q < 3; ++q) { s1[h] += red[q][l][h]; s2[h] += red[q][l][h+8]; }
        f1[h*4096 + i] = s1[h];
        f2[h*4096 + i] = s2[h];
      }
    }
  }
}

// k_gtab: per-head f2 max + G tables Gp=exp(f2), Gn=exp(a*f2) in f16
__global__ __launch_bounds__(256) void k_gtab(const float* __restrict__ f2,
                                              float* __restrict__ fmx,
                                              _Float16* __restrict__ Gp,
                                              _Float16* __restrict__ Gn) {
  int h = blockIdx.x, t = threadIdx.x;
  const float* f = f2 + h * 4096;
  float m = -1e30f;
  for (int i = t; i < 4096; i += 256) m = fmaxf(m, f[i]);
#pragma unroll
  for (int off = 32; off >= 1; off >>= 1) m = fmaxf(m, __shfl_xor(m, off, 64));
  __shared__ float sm[4];
  if ((t & 63) == 0) sm[t >> 6] = m;
  __syncthreads();
  if (t == 0) fmx[h] = fmaxf(fmaxf(sm[0], sm[1]), fmaxf(sm[2], sm[3]));
  for (int i = t; i < 4096; i += 256) {
    float v = f[i];
    Gp[h*4096 + i] = (_Float16)__expf(v);
    Gn[h*4096 + i] = (_Float16)__expf(ALPHA * v);
  }
}

// k_attn: block=(head, 64 rows); 4 waves = 2 rowgroups(32) x 2 j-halves(2048)
__global__ __launch_bounds__(256) void k_attn(
    const float* __restrict__ f1, const float* __restrict__ f2max,
    const unsigned int* __restrict__ adjbits, const _Float16* __restrict__ Gp,
    const _Float16* __restrict__ Gn, const _Float16* __restrict__ bfrag,
    float* __restrict__ hpart) {
  __shared__ unsigned int Lb[64][132];
  __shared__ f32x4 red[2][64][10];
  __shared__ unsigned MLUT[4];
  int b = blockIdx.x;
  int h = b & 7, rb = b >> 3;                       // head <-> XCD L2 locality
  int i0 = rb * 64;
  int t = threadIdx.x, w = t >> 6, l = t & 63;
  int rg = w & 1, jh = w >> 1;
  int r = l & 15, g = l >> 4, g8 = g * 8;
  if (t < 4) MLUT[t] = ((t & 1) ? 0xFFFFu : 0u) | ((t & 2) ? 0xFFFF0000u : 0u);
  for (int q = t; q < 64 * 128; q += 256)
    Lb[q >> 7][q & 127] = adjbits[(size_t)(i0 + (q >> 7)) * 128 + (q & 127)];
  __syncthreads();
  int row0 = i0 + rg * 32 + r, row1 = row0 + 16;
  float F2m = f2max[h];
  float f1r0 = f1[h * N_NODES + row0];
  float f1r1 = f1[h * N_NODES + row1];
  float sM0 = f1r0 + F2m, sM1 = f1r1 + F2m;
  float M0 = fmaxf(sM0, ALPHA * sM0), M1 = fmaxf(sM1, ALPHA * sM1);
  unsigned short ep0 = f2h_bits(__expf(f1r0 - M0));
  unsigned short en0 = f2h_bits(__expf(ALPHA * f1r0 - M0));
  unsigned short ep1 = f2h_bits(__expf(f1r1 - M1));
  unsigned short en1 = f2h_bits(__expf(ALPHA * f1r1 - M1));
  unsigned Epp0 = ep0 | ((unsigned)ep0 << 16), Enn0 = en0 | ((unsigned)en0 << 16);
  unsigned Epp1 = ep1 | ((unsigned)ep1 << 16), Enn1 = en1 | ((unsigned)en1 << 16);
  const uint4* GpV = (const uint4*)(Gp + (size_t)h * 4096);
  const uint4* GnV = (const uint4*)(Gn + (size_t)h * 4096);
  const uint4* bfh = (const uint4*)bfrag + (size_t)h * (128 * 4 * 64) + l;
  unsigned ov = (r == 0) ? 0x3C003C00u : 0u;        // ones column B-frag (f16 1.0)
  U4 bones; bones.u = make_uint4(ov, ov, ov, ov);
  f32x4 z = {0.f,0.f,0.f,0.f};
  f32x4 a0[4] = {z,z,z,z}, a1[4] = {z,z,z,z}, d0 = z, d1 = z;
  int r0i = rg * 32 + r;
  for (int jt = jh * 64; jt < jh * 64 + 64; ++jt) {
    unsigned w0 = Lb[r0i][jt];
    unsigned w1 = Lb[r0i + 16][jt];
    U4 gp, gn, av0, av1;
    gp.u = GpV[jt * 4 + g];
    gn.u = GnV[jt * 4 + g];
#pragma unroll
    for (int p = 0; p < 4; ++p) {
      unsigned pm0 = pkmax(pkmul(Epp0, gp.w[p]), pkmul(Enn0, gn.w[p]));
      unsigned pm1 = pkmax(pkmul(Epp1, gp.w[p]), pkmul(Enn1, gn.w[p]));
      av0.w[p] = pm0 & MLUT[(w0 >> (g8 + 2*p)) & 3];
      av1.w[p] = pm1 & MLUT[(w1 >> (g8 + 2*p)) & 3];
    }
    const uint4* bp = bfh + (size_t)jt * 256;
    U4 b0, b1, b2, b3;
    b0.u = bp[0]; b1.u = bp[64]; b2.u = bp[128]; b3.u = bp[192];
    a0[0] = __builtin_amdgcn_mfma_f32_16x16x32_f16(av0.h, b0.h, a0[0], 0, 0, 0);
    a0[1] = __builtin_amdgcn_mfma_f32_16x16x32_f16(av0.h, b1.h, a0[1], 0, 0, 0);
    a0[2] = __builtin_amdgcn_mfma_f32_16x16x32_f16(av0.h, b2.h, a0[2], 0, 0, 0);
    a0[3] = __builtin_amdgcn_mfma_f32_16x16x32_f16(av0.h, b3.h, a0[3], 0, 0, 0);
    d0    = __builtin_amdgcn_mfma_f32_16x16x32_f16(av0.h, bones.h, d0, 0, 0, 0);
    a1[0] = __builtin_amdgcn_mfma_f32_16x16x32_f16(av1.h, b0.h, a1[0], 0, 0, 0);
    a1[1] = __builtin_amdgcn_mfma_f32_16x16x32_f16(av1.h, b1.h, a1[1], 0, 0, 0);
    a1[2] = __builtin_amdgcn_mfma_f32_16x16x32_f16(av1.h, b2.h, a1[2], 0, 0, 0);
    a1[3] = __builtin_amdgcn_mfma_f32_16x16x32_f16(av1.h, b3.h, a1[3], 0, 0, 0);
    d1    = __builtin_amdgcn_mfma_f32_16x16x32_f16(av1.h, bones.h, d1, 0, 0, 0);
  }
  if (jh == 1) {
#pragma unroll
    for (int q = 0; q < 4; ++q) { red[rg][l][q] = a0[q]; red[rg][l][4+q] = a1[q]; }
    red[rg][l][8] = d0; red[rg][l][9] = d1;
  }
  __syncthreads();
  if (jh == 0) {
#pragma unroll
    for (int q = 0; q < 4; ++q) { a0[q] += red[rg][l][q]; a1[q] += red[rg][l][4+q]; }
    d0 += red[rg][l][8]; d1 += red[rg][l][9];
#pragma unroll
    for (int ri = 0; ri < 4; ++ri) {
      float den0 = __shfl(d0[ri], (l & 48));        // col 0 of D holds row-sum
      float den1 = __shfl(d1[ri], (l & 48));
      float sc0 = 0.125f / den0, sc1 = 0.125f / den1;
      float* hp0 = hpart + ((size_t)h * N_NODES + i0 + rg*32 + g*4 + ri) * 64;
      float* hp1 = hp0 + 16 * 64;
      hp0[r] = a0[0][ri]*sc0; hp0[16+r] = a0[1][ri]*sc0;
      hp0[32+r] = a0[2][ri]*sc0; hp0[48+r] = a0[3][ri]*sc0;
      hp1[r] = a1[0][ri]*sc1; hp1[16+r] = a1[1][ri]*sc1;
      hp1[32+r] = a1[2][ri]*sc1; hp1[48+r] = a1[3][ri]*sc1;
    }
  }
}

// out = sum_h hpart[h]  (0.125 already folded in)
__global__ __launch_bounds__(256) void k_hmean(const float* __restrict__ hpart,
                                               float* __restrict__ out) {
  int idx = blockIdx.x * 256 + threadIdx.x;
  const float4* hp = (const float4*)hpart;
  float4 s = hp[idx];
#pragma unroll
  for (int h = 1; h < 8; ++h) {
    float4 v = hp[h * 65536 + idx];
    s.x += v.x; s.y += v.y; s.z += v.z; s.w += v.w;
  }
  ((float4*)out)[idx] = s;
}

extern "C" void kernel_launch(void* const* d_in, const int* in_sizes, int n_in,
                              void* d_out, int out_size, void* d_ws, size_t ws_size,
                              hipStream_t stream) {
  const float* X = (const float*)d_in[0];
  const int* adj = (const int*)d_in[1];
  const float* W = (const float*)d_in[2];
  const float* a = (const float*)d_in[3];
  float* out = (float*)d_out;
  char* ws = (char*)d_ws;

  _Float16* Xf    = (_Float16*)(ws + XF_OFF);
  _Float16* wfrag = (_Float16*)(ws + WFRAG_OFF);
  _Float16* bfrag = (_Float16*)(ws + BFRAG_OFF);
  float* f1  = (float*)(ws + F1_OFF);
  float* f2  = (float*)(ws + F2_OFF);
  float* wa1 = (float*)(ws + WA1_OFF);
  float* wa2 = (float*)(ws + WA2_OFF);
  float* fmx = (float*)(ws + FMAX_OFF);
  _Float16* Gp = (_Float16*)(ws + GP_OFF);
  _Float16* Gn = (_Float16*)(ws + GN_OFF);
  unsigned long long* bits64 = (unsigned long long*)(ws + ADJ_OFF);
  const unsigned int* bits32 = (const unsigned int*)(ws + ADJ_OFF);
  float* hpart = (float*)(ws + HPART_OFF);

  k_misc<<<dim3(2128), dim3(256), 0, stream>>>(X, adj, W, a, Xf, bits64, wa1, wa2, wfrag);
  k_hf<<<dim3(320), dim3(256), 0, stream>>>(Xf, wfrag, X, wa1, wa2, bfrag, f1, f2);
  k_gtab<<<dim3(8), dim3(256), 0, stream>>>(f2, fmx, Gp, Gn);
  k_attn<<<dim3(512), dim3(256), 0, stream>>>(f1, fmx, bits32, Gp, Gn, bfrag, hpart);
  k_hmean<<<dim3(256), dim3(256), 0, stream>>>(hpart, out);
}